// Round 2
// baseline (727.101 us; speedup 1.0000x reference)
//
#include <hip/hip_runtime.h>
#include <hip/hip_bf16.h>

typedef __attribute__((ext_vector_type(4))) float f32x4;
typedef __attribute__((ext_vector_type(8))) short bfrag;   // 8 bf16 = 4 VGPRs
typedef __attribute__((ext_vector_type(4))) float facc;    // MFMA C/D
typedef __attribute__((ext_vector_type(8))) ushort u16x8;  // 16B of bf16

#define N_MOVES 200000
#define N_EDGES 1600000
#define DEMB 256
#define KD 512          // 2*D, also layer-2 K
#define H1D 512
#define H2D 256
#define MT 32           // moves per block (32 -> ~66KB LDS -> 2 blocks/CU)
#define NTHREADS 512    // 8 waves

__device__ __forceinline__ ushort f2b(float f) {   // f32 -> bf16 RNE
  union { float f; unsigned u; } x; x.f = f;
  unsigned r = (x.u + 0x7fffu + ((x.u >> 16) & 1u)) >> 16;
  return (ushort)r;
}
__device__ __forceinline__ float b2f(ushort h) {
  union { unsigned u; float f; } x; x.u = ((unsigned)h) << 16;
  return x.f;
}

// ---- prep: W1 [512,512] f32 -> bf16 ; W2 [256,512] f32 -> bf16 (into ws) ----
__global__ void convert_w(const float* __restrict__ W1, const float* __restrict__ W2,
                          ushort* __restrict__ Wb) {
  int i = (blockIdx.x * 256 + threadIdx.x) * 4;
  const int n1 = H1D * KD;  // 262144
  if (i < n1) {
    f32x4 v = *(const f32x4*)(W1 + i);
    ushort4 h = { f2b(v.x), f2b(v.y), f2b(v.z), f2b(v.w) };
    *(ushort4*)(Wb + i) = h;
  } else {
    int j = i - n1;          // < 131072
    f32x4 v = *(const f32x4*)(W2 + j);
    ushort4 h = { f2b(v.x), f2b(v.y), f2b(v.z), f2b(v.w) };
    *(ushort4*)(Wb + n1 + j) = h;
  }
}

// ---- prep: embedding table f32 -> bf16 (25.6M elems) ----
__global__ void convert_emb(const float* __restrict__ E, ushort* __restrict__ Eb) {
  int i = (blockIdx.x * 256 + threadIdx.x) * 8;
  f32x4 a = *(const f32x4*)(E + i);
  f32x4 b = *(const f32x4*)(E + i + 4);
  u16x8 h = { f2b(a.x), f2b(a.y), f2b(a.z), f2b(a.w),
              f2b(b.x), f2b(b.y), f2b(b.z), f2b(b.w) };
  *(u16x8*)(Eb + i) = h;
}

// ---- fused gather + 3-layer MLP ----
// block: 32 moves, 512 threads (8 waves). LDS ~66KB -> 2 blocks/CU.
template<int EMBBF>
__global__ __launch_bounds__(NTHREADS, 2)
void fused_mlp(const float* __restrict__ emb,        // f32 table (fallback)
               const ushort* __restrict__ embb,      // bf16 table (fast path)
               const int* __restrict__ edge_index,   // [2][N_EDGES]
               const int* __restrict__ move_idx,     // [N_MOVES]
               const ushort* __restrict__ W1b,       // [512][512] bf16
               const float* __restrict__ b1,
               const ushort* __restrict__ W2b,       // [256][512] bf16
               const float* __restrict__ b2,
               const float* __restrict__ W3,         // [256] f32
               const float* __restrict__ b3,
               float* __restrict__ out)
{
  __shared__ ushort bufA[MT][KD];   // 32KB: X (layer1 A), then H2
  __shared__ ushort bufB[MT][KD];   // 32KB: H1 (layer2 A)
  __shared__ int   s_src[MT], s_tgt[MT];
  __shared__ float sW3[H2D];

  const int tid  = threadIdx.x;
  const int lane = tid & 63;
  const int wave = tid >> 6;        // 0..7
  const int m0   = blockIdx.x * MT;

  if (tid < MT) {
    int e = move_idx[m0 + tid];
    s_src[tid] = edge_index[e];
    s_tgt[tid] = edge_index[N_EDGES + e];
  }
  if (tid < H2D) sW3[tid] = W3[tid];
  __syncthreads();

  // ---- gather X[row] = concat(emb[src], emb[tgt]) as bf16, XOR-swizzled ----
  if (EMBBF) {
    for (int u = tid; u < MT * 64; u += NTHREADS) {   // 16B chunks
      int row = u >> 6;
      int c8  = u & 63;                                // 64 x 16B = 1KB/row
      const ushort* sp = (c8 < 32) ? (embb + (size_t)s_src[row] * DEMB + (c8 << 3))
                                   : (embb + (size_t)s_tgt[row] * DEMB + ((c8 - 32) << 3));
      u16x8 v = *(const u16x8*)sp;
      int bo = (c8 << 4) ^ ((row & 7) << 4);
      *(u16x8*)((char*)(&bufA[row][0]) + bo) = v;
    }
  } else {
    for (int u = tid; u < MT * 128; u += NTHREADS) {  // f32 fallback
      int row = u >> 7;
      int c4  = u & 127;
      const float* sp = (c4 < 64) ? (emb + (size_t)s_src[row] * DEMB + (c4 << 2))
                                  : (emb + (size_t)s_tgt[row] * DEMB + ((c4 - 64) << 2));
      f32x4 v = *(const f32x4*)sp;
      ushort4 h = { f2b(v.x), f2b(v.y), f2b(v.z), f2b(v.w) };
      int bo = (c4 << 3) ^ ((row & 7) << 4);
      *(ushort4*)((char*)(&bufA[row][0]) + bo) = h;
    }
  }
  __syncthreads();

  const int arow = lane & 15;            // M/N index within fragment
  const int ak   = (lane >> 4) << 3;     // k chunk base: 0,8,16,24

  // ================= layer 1: H1[32][512] = relu(X @ W1^T + b1) =================
  // wave owns 64 output cols: n0 = wave*64; acc[2 m-groups][4 n-groups]
  {
    facc acc[2][4] = {};
    const int n0 = wave << 6;
    #pragma unroll 4
    for (int kk = 0; kk < 16; ++kk) {    // K step 32
      bfrag a[2], b[4];
      #pragma unroll
      for (int mg = 0; mg < 2; ++mg) {
        int row = (mg << 4) + arow;
        int bo = ((kk << 6) + (ak << 1)) ^ ((row & 7) << 4);
        a[mg] = *(const bfrag*)((const char*)(&bufA[row][0]) + bo);
      }
      #pragma unroll
      for (int ng = 0; ng < 4; ++ng) {
        int wrow = n0 + (ng << 4) + arow;                  // W1 out-dim row
        b[ng] = *(const bfrag*)(W1b + (size_t)wrow * KD + (kk << 5) + ak);
      }
      #pragma unroll
      for (int mg = 0; mg < 2; ++mg)
        #pragma unroll
        for (int ng = 0; ng < 4; ++ng)
          acc[mg][ng] = __builtin_amdgcn_mfma_f32_16x16x32_bf16(a[mg], b[ng], acc[mg][ng], 0, 0, 0);
    }
    // epilogue: +bias, relu, ->bf16 into bufB (swizzled)
    #pragma unroll
    for (int ng = 0; ng < 4; ++ng) {
      int col = n0 + (ng << 4) + arow;
      float bias = b1[col];
      #pragma unroll
      for (int mg = 0; mg < 2; ++mg) {
        #pragma unroll
        for (int r = 0; r < 4; ++r) {
          int row = (mg << 4) + ((lane >> 4) << 2) + r;    // C/D: row=(lane>>4)*4+r
          float v = fmaxf(acc[mg][ng][r] + bias, 0.f);
          int bo = (col << 1) ^ ((row & 7) << 4);
          *(ushort*)((char*)(&bufB[row][0]) + bo) = f2b(v);
        }
      }
    }
  }
  __syncthreads();

  // ================= layer 2: H2[32][256] = relu(H1 @ W2^T + b2) =================
  ushort (*H2s)[H2D] = (ushort(*)[H2D])bufA;   // reuse X buffer (16KB)
  {
    facc acc2[2][2] = {};
    const int p0 = wave << 5;                  // 32 cols per wave
    #pragma unroll 4
    for (int kk = 0; kk < 16; ++kk) {
      bfrag a[2], b[2];
      #pragma unroll
      for (int mg = 0; mg < 2; ++mg) {
        int row = (mg << 4) + arow;
        int bo = ((kk << 6) + (ak << 1)) ^ ((row & 7) << 4);
        a[mg] = *(const bfrag*)((const char*)(&bufB[row][0]) + bo);
      }
      #pragma unroll
      for (int ng = 0; ng < 2; ++ng) {
        int wrow = p0 + (ng << 4) + arow;
        b[ng] = *(const bfrag*)(W2b + (size_t)wrow * KD + (kk << 5) + ak);
      }
      #pragma unroll
      for (int mg = 0; mg < 2; ++mg)
        #pragma unroll
        for (int ng = 0; ng < 2; ++ng)
          acc2[mg][ng] = __builtin_amdgcn_mfma_f32_16x16x32_bf16(a[mg], b[ng], acc2[mg][ng], 0, 0, 0);
    }
    #pragma unroll
    for (int ng = 0; ng < 2; ++ng) {
      int col = p0 + (ng << 4) + arow;
      float bias = b2[col];
      #pragma unroll
      for (int mg = 0; mg < 2; ++mg) {
        #pragma unroll
        for (int r = 0; r < 4; ++r) {
          int row = (mg << 4) + ((lane >> 4) << 2) + r;
          float v = fmaxf(acc2[mg][ng][r] + bias, 0.f);
          int bo = (col << 1) ^ ((row & 7) << 4);
          *(ushort*)((char*)(&H2s[row][0]) + bo) = f2b(v);
        }
      }
    }
  }
  __syncthreads();

  // ================= layer 3: out[m] = H2[m] . W3 + b3 (16 lanes per move) =================
  {
    const float b3v = b3[0];
    int row = tid >> 4;          // 0..31
    int six = tid & 15;          // 16 k's each
    float sum = 0.f;
    #pragma unroll
    for (int j = 0; j < 2; ++j) {
      int kb = (six << 5) + (j << 4);                 // byte offset of k*2
      int bo = kb ^ ((row & 7) << 4);
      bfrag hv = *(const bfrag*)((const char*)(&H2s[row][0]) + bo);
      int k0 = (six << 4) + (j << 3);
      #pragma unroll
      for (int e = 0; e < 8; ++e)
        sum += b2f((ushort)hv[e]) * sW3[k0 + e];
    }
    sum += __shfl_xor(sum, 1);
    sum += __shfl_xor(sum, 2);
    sum += __shfl_xor(sum, 4);
    sum += __shfl_xor(sum, 8);
    if (six == 0) out[m0 + row] = sum + b3v;
  }
}

extern "C" void kernel_launch(void* const* d_in, const int* in_sizes, int n_in,
                              void* d_out, int out_size, void* d_ws, size_t ws_size,
                              hipStream_t stream) {
  const float* emb        = (const float*)d_in[0];
  const int*   edge_index = (const int*)d_in[1];
  const int*   move_idx   = (const int*)d_in[2];
  const float* W1         = (const float*)d_in[3];
  const float* b1         = (const float*)d_in[4];
  const float* W2         = (const float*)d_in[5];
  const float* b2         = (const float*)d_in[6];
  const float* W3         = (const float*)d_in[7];
  const float* b3         = (const float*)d_in[8];
  float* out = (float*)d_out;

  ushort* Wb   = (ushort*)d_ws;                 // W1b [512*512] + W2b [256*512]
  ushort* Embb = Wb + (H1D * KD + H2D * KD);    // bf16 emb table [100000*256]
  const size_t need = (size_t)(H1D * KD + H2D * KD + 100000 * DEMB) * 2;

  convert_w<<<384, 256, 0, stream>>>(W1, W2, Wb);

  if (ws_size >= need) {
    convert_emb<<<12500, 256, 0, stream>>>(emb, Embb);
    fused_mlp<1><<<N_MOVES / MT, NTHREADS, 0, stream>>>(
        emb, Embb, edge_index, move_idx,
        Wb, b1, Wb + H1D * KD, b2, W3, b3, out);
  } else {
    fused_mlp<0><<<N_MOVES / MT, NTHREADS, 0, stream>>>(
        emb, Embb, edge_index, move_idx,
        Wb, b1, Wb + H1D * KD, b2, W3, b3, out);
  }
}

// Round 4
// 512.187 us; speedup vs baseline: 1.4196x; 1.4196x over previous
//
#include <hip/hip_runtime.h>
#include <hip/hip_bf16.h>

typedef __attribute__((ext_vector_type(4))) float f32x4;
typedef __attribute__((ext_vector_type(8))) short bfrag;   // 8 bf16 = 4 VGPRs
typedef __attribute__((ext_vector_type(4))) float facc;    // MFMA C/D
typedef __attribute__((ext_vector_type(8))) ushort u16x8;  // 16B of bf16

#define N_MOVES 200000
#define N_EDGES 1600000
#define DEMB 256
#define KD 512          // 2*D, also layer-2 K
#define H1D 512
#define H2D 256
#define MT 64           // moves per block
#define NTHREADS 1024   // 16 waves, 4/SIMD (1 block/CU due to 132KB LDS)

__device__ __forceinline__ ushort f2b(float f) {   // f32 -> bf16 RNE
  union { float f; unsigned u; } x; x.f = f;
  unsigned r = (x.u + 0x7fffu + ((x.u >> 16) & 1u)) >> 16;
  return (ushort)r;
}
__device__ __forceinline__ float b2f(ushort h) {
  union { unsigned u; float f; } x; x.u = ((unsigned)h) << 16;
  return x.f;
}

// ---- prep: W1 [512,512] f32 -> bf16 ; W2 [256,512] f32 -> bf16 (into ws) ----
__global__ void convert_w(const float* __restrict__ W1, const float* __restrict__ W2,
                          ushort* __restrict__ Wb) {
  int i = (blockIdx.x * 256 + threadIdx.x) * 4;
  const int n1 = H1D * KD;  // 262144
  if (i < n1) {
    f32x4 v = *(const f32x4*)(W1 + i);
    ushort4 h = { f2b(v.x), f2b(v.y), f2b(v.z), f2b(v.w) };
    *(ushort4*)(Wb + i) = h;
  } else {
    int j = i - n1;          // < 131072
    f32x4 v = *(const f32x4*)(W2 + j);
    ushort4 h = { f2b(v.x), f2b(v.y), f2b(v.z), f2b(v.w) };
    *(ushort4*)(Wb + n1 + j) = h;
  }
}

// ---- prep: embedding table f32 -> bf16 (25.6M elems) ----
__global__ void convert_emb(const float* __restrict__ E, ushort* __restrict__ Eb) {
  int i = (blockIdx.x * 256 + threadIdx.x) * 8;
  f32x4 a = *(const f32x4*)(E + i);
  f32x4 b = *(const f32x4*)(E + i + 4);
  u16x8 h = { f2b(a.x), f2b(a.y), f2b(a.z), f2b(a.w),
              f2b(b.x), f2b(b.y), f2b(b.z), f2b(b.w) };
  *(u16x8*)(Eb + i) = h;
}

// ---- fused gather + 3-layer MLP, register-prefetched ----
template<int EMBBF>
__global__ __launch_bounds__(NTHREADS, 2)
void fused_mlp(const float* __restrict__ emb,        // f32 table (fallback)
               const ushort* __restrict__ embb,      // bf16 table (fast path)
               const int* __restrict__ edge_index,   // [2][N_EDGES]
               const int* __restrict__ move_idx,     // [N_MOVES]
               const ushort* __restrict__ W1b,       // [512][512] bf16
               const float* __restrict__ b1,
               const ushort* __restrict__ W2b,       // [256][512] bf16
               const float* __restrict__ b2,
               const float* __restrict__ W3,         // [256] f32
               const float* __restrict__ b3,
               float* __restrict__ out)
{
  __shared__ ushort bufA[MT][KD];   // 64KB: X (layer1 A), then H2
  __shared__ ushort bufB[MT][KD];   // 64KB: H1 (layer2 A)
  __shared__ int   s_src[MT], s_tgt[MT];
  __shared__ float sW3[H2D];

  const int tid  = threadIdx.x;
  const int lane = tid & 63;
  const int wave = tid >> 6;        // 0..15
  const int m0   = blockIdx.x * MT;

  if (tid < MT) {
    int e = move_idx[m0 + tid];
    s_src[tid] = edge_index[e];
    s_tgt[tid] = edge_index[N_EDGES + e];
  }
  if (tid < H2D) sW3[tid] = W3[tid];
  __syncthreads();

  const int arow = lane & 15;            // M/N index within fragment
  const int akE  = (lane >> 4) << 3;     // k element base within 32-k step
  const int akB  = (lane >> 4) << 4;     // same, bytes

  // ---- W1 prologue prefetch (kk=0,1) issued BEFORE gather: in flight during it ----
  const ushort* w1base = W1b + (size_t)(((wave << 5) + arow) * KD) + akE;  // wave owns 32 cols
  bfrag b1a[2], b1b[2];
  #pragma unroll
  for (int ng = 0; ng < 2; ++ng) {
    b1a[ng] = *(const bfrag*)(w1base + (ng << 4) * KD);
    b1b[ng] = *(const bfrag*)(w1base + (ng << 4) * KD + 32);
  }
  float bias1[2];
  #pragma unroll
  for (int ng = 0; ng < 2; ++ng) bias1[ng] = b1[(wave << 5) + (ng << 4) + arow];

  // ---- gather X[row] = concat(emb[src], emb[tgt]) as bf16, XOR-swizzled ----
  if (EMBBF) {
    #pragma unroll
    for (int it = 0; it < (MT * 64) / NTHREADS; ++it) {      // 4 iters
      int u   = tid + it * NTHREADS;
      int row = u >> 6;
      int c8  = u & 63;
      const ushort* sp = (c8 < 32) ? (embb + (size_t)s_src[row] * DEMB + (c8 << 3))
                                   : (embb + (size_t)s_tgt[row] * DEMB + ((c8 - 32) << 3));
      u16x8 v = *(const u16x8*)sp;
      int bo = (c8 << 4) ^ ((row & 7) << 4);
      *(u16x8*)((char*)(&bufA[row][0]) + bo) = v;
    }
  } else {
    #pragma unroll
    for (int it = 0; it < (MT * 128) / NTHREADS; ++it) {     // 8 iters
      int u   = tid + it * NTHREADS;
      int row = u >> 7;
      int c4  = u & 127;
      const float* sp = (c4 < 64) ? (emb + (size_t)s_src[row] * DEMB + (c4 << 2))
                                  : (emb + (size_t)s_tgt[row] * DEMB + ((c4 - 64) << 2));
      f32x4 v = *(const f32x4*)sp;
      ushort4 h = { f2b(v.x), f2b(v.y), f2b(v.z), f2b(v.w) };
      int bo = (c4 << 3) ^ ((row & 7) << 4);
      *(ushort4*)((char*)(&bufA[row][0]) + bo) = h;
    }
  }
  __syncthreads();

  // ================= layer 1: H1[64][512] = relu(X @ W1^T + b1) =================
  // 16 waves x 32 cols. acc[4 mg][2 ng]. B prefetched 2 kk ahead, A 1 ahead.
  {
    facc acc[4][2] = {};
    bfrag a_c[4], a_n[4], b_n[2];
    #pragma unroll
    for (int mg = 0; mg < 4; ++mg) {
      int row = (mg << 4) + arow;
      int bo = akB ^ ((row & 7) << 4);
      a_c[mg] = *(const bfrag*)((const char*)(&bufA[row][0]) + bo);
    }
    #pragma unroll
    for (int kk = 0; kk < 16; ++kk) {
      if (kk < 15) {
        #pragma unroll
        for (int mg = 0; mg < 4; ++mg) {
          int row = (mg << 4) + arow;
          int bo = (((kk + 1) << 6) + akB) ^ ((row & 7) << 4);
          a_n[mg] = *(const bfrag*)((const char*)(&bufA[row][0]) + bo);
        }
      }
      if (kk < 14) {
        #pragma unroll
        for (int ng = 0; ng < 2; ++ng)
          b_n[ng] = *(const bfrag*)(w1base + (ng << 4) * KD + ((kk + 2) << 5));
      }
      #pragma unroll
      for (int mg = 0; mg < 4; ++mg)
        #pragma unroll
        for (int ng = 0; ng < 2; ++ng)
          acc[mg][ng] = __builtin_amdgcn_mfma_f32_16x16x32_bf16(a_c[mg], b1a[ng], acc[mg][ng], 0, 0, 0);
      #pragma unroll
      for (int mg = 0; mg < 4; ++mg) a_c[mg] = a_n[mg];
      #pragma unroll
      for (int ng = 0; ng < 2; ++ng) { b1a[ng] = b1b[ng]; b1b[ng] = b_n[ng]; }
    }

    // ---- W2 prologue prefetch (kk=0,1) issued before epilogue-1 ----
    const ushort* w2base = W2b + (size_t)(((wave << 4) + arow) * KD) + akE;  // wave owns 16 cols
    bfrag b2a = *(const bfrag*)(w2base);
    bfrag b2b = *(const bfrag*)(w2base + 32);
    float bias2 = b2[(wave << 4) + arow];

    // epilogue: +bias, relu, ->bf16 into bufB (swizzled)
    #pragma unroll
    for (int ng = 0; ng < 2; ++ng) {
      int col = (wave << 5) + (ng << 4) + arow;
      #pragma unroll
      for (int mg = 0; mg < 4; ++mg) {
        #pragma unroll
        for (int r = 0; r < 4; ++r) {
          int row = (mg << 4) + ((lane >> 4) << 2) + r;    // C/D: row=(lane>>4)*4+r
          float v = fmaxf(acc[mg][ng][r] + bias1[ng], 0.f);
          int bo = (col << 1) ^ ((row & 7) << 4);
          *(ushort*)((char*)(&bufB[row][0]) + bo) = f2b(v);
        }
      }
    }
    __syncthreads();

    // ================= layer 2: H2[64][256] = relu(H1 @ W2^T + b2) =================
    ushort (*H2s)[H2D] = (ushort(*)[H2D])bufA;   // reuse X buffer (32KB)
    {
      facc acc2[4] = {};
      bfrag a2c[4], a2n[4], b2n;
      #pragma unroll
      for (int mg = 0; mg < 4; ++mg) {
        int row = (mg << 4) + arow;
        int bo = akB ^ ((row & 7) << 4);
        a2c[mg] = *(const bfrag*)((const char*)(&bufB[row][0]) + bo);
      }
      #pragma unroll
      for (int kk = 0; kk < 16; ++kk) {
        if (kk < 15) {
          #pragma unroll
          for (int mg = 0; mg < 4; ++mg) {
            int row = (mg << 4) + arow;
            int bo = (((kk + 1) << 6) + akB) ^ ((row & 7) << 4);
            a2n[mg] = *(const bfrag*)((const char*)(&bufB[row][0]) + bo);
          }
        }
        if (kk < 14) b2n = *(const bfrag*)(w2base + ((kk + 2) << 5));
        #pragma unroll
        for (int mg = 0; mg < 4; ++mg)
          acc2[mg] = __builtin_amdgcn_mfma_f32_16x16x32_bf16(a2c[mg], b2a, acc2[mg], 0, 0, 0);
        #pragma unroll
        for (int mg = 0; mg < 4; ++mg) a2c[mg] = a2n[mg];
        b2a = b2b; b2b = b2n;
      }
      int col = (wave << 4) + arow;
      #pragma unroll
      for (int mg = 0; mg < 4; ++mg) {
        #pragma unroll
        for (int r = 0; r < 4; ++r) {
          int row = (mg << 4) + ((lane >> 4) << 2) + r;
          float v = fmaxf(acc2[mg][r] + bias2, 0.f);
          int bo = (col << 1) ^ ((row & 7) << 4);
          *(ushort*)((char*)(&H2s[row][0]) + bo) = f2b(v);
        }
      }
    }
  }
  __syncthreads();

  // ================= layer 3: out[m] = H2[m] . W3 + b3 (16 lanes per move) =================
  {
    ushort (*H2s)[H2D] = (ushort(*)[H2D])bufA;
    const float b3v = b3[0];
    int row = tid >> 4;          // 0..63
    int six = tid & 15;          // 16 k's each
    float sum = 0.f;
    #pragma unroll
    for (int j = 0; j < 2; ++j) {
      int kb = (six << 5) + (j << 4);                 // byte offset
      int bo = kb ^ ((row & 7) << 4);
      bfrag hv = *(const bfrag*)((const char*)(&H2s[row][0]) + bo);
      int k0 = (six << 4) + (j << 3);
      #pragma unroll
      for (int e = 0; e < 8; ++e)
        sum += b2f((ushort)hv[e]) * sW3[k0 + e];
    }
    sum += __shfl_xor(sum, 1);
    sum += __shfl_xor(sum, 2);
    sum += __shfl_xor(sum, 4);
    sum += __shfl_xor(sum, 8);
    if (six == 0) out[m0 + row] = sum + b3v;
  }
}

extern "C" void kernel_launch(void* const* d_in, const int* in_sizes, int n_in,
                              void* d_out, int out_size, void* d_ws, size_t ws_size,
                              hipStream_t stream) {
  const float* emb        = (const float*)d_in[0];
  const int*   edge_index = (const int*)d_in[1];
  const int*   move_idx   = (const int*)d_in[2];
  const float* W1         = (const float*)d_in[3];
  const float* b1         = (const float*)d_in[4];
  const float* W2         = (const float*)d_in[5];
  const float* b2         = (const float*)d_in[6];
  const float* W3         = (const float*)d_in[7];
  const float* b3         = (const float*)d_in[8];
  float* out = (float*)d_out;

  ushort* Wb   = (ushort*)d_ws;                 // W1b [512*512] + W2b [256*512]
  ushort* Embb = Wb + (H1D * KD + H2D * KD);    // bf16 emb table [100000*256]
  const size_t need = (size_t)(H1D * KD + H2D * KD + 100000 * DEMB) * 2;

  convert_w<<<384, 256, 0, stream>>>(W1, W2, Wb);

  if (ws_size >= need) {
    convert_emb<<<12500, 256, 0, stream>>>(emb, Embb);
    fused_mlp<1><<<N_MOVES / MT, NTHREADS, 0, stream>>>(
        emb, Embb, edge_index, move_idx,
        Wb, b1, Wb + H1D * KD, b2, W3, b3, out);
  } else {
    fused_mlp<0><<<N_MOVES / MT, NTHREADS, 0, stream>>>(
        emb, Embb, edge_index, move_idx,
        Wb, b1, Wb + H1D * KD, b2, W3, b3, out);
  }
}